// Round 15
// baseline (171.566 us; speedup 1.0000x reference)
//
#include <hip/hip_runtime.h>
#include <hip/hip_bf16.h>
#include <stdint.h>

// Problem constants: B=4, T=2048, C=1024, H=16, HD=64
#define BB 4
#define TT 2048
#define CC 1024
#define HH 16
#define HD 64
#define MM (BB*TT)      /* 8192 */
#define N1 (3*CC)       /* 3072 */

typedef short bf16x8 __attribute__((ext_vector_type(8)));
typedef float f32x4  __attribute__((ext_vector_type(4)));
typedef float f32x4v __attribute__((ext_vector_type(4)));
typedef uint32_t u32x2 __attribute__((ext_vector_type(2)));

using bf16 = __hip_bfloat16;

static __device__ __forceinline__ short f2bf(float f) {
  union { float f; uint32_t u; } v; v.f = f;
  uint32_t u = v.u;
  u += 0x7fffu + ((u >> 16) & 1u);
  return (short)(u >> 16);
}

static __device__ __forceinline__ uint32_t cvt_pk_bf16(float lo, float hi) {
  uint32_t r;
  asm("v_cvt_pk_bf16_f32 %0, %1, %2" : "=v"(r) : "v"(lo), "v"(hi));
  return r;
}

static __device__ __forceinline__ void gload_lds16(const void* g, void* l) {
  __builtin_amdgcn_global_load_lds(
      (const __attribute__((address_space(1))) uint32_t*)g,
      (__attribute__((address_space(3))) uint32_t*)l, 16, 0, 0);
}

// ---------------- prep: xcast + both weight transposes, one launch ----------
static __device__ __forceinline__ void wtrans_body(const float* __restrict__ in,
                                                   bf16* __restrict__ out,
                                                   int K, int N, int bj, int bi,
                                                   int tid) {
  __shared__ float tl[32][33];
  const int tx = tid & 31, ty = tid >> 5;
  const float* ip = in + (size_t)(bi * 32) * N + bj * 32;
#pragma unroll
  for (int r0 = 0; r0 < 4; ++r0) {
    int r = ty + r0 * 8;
    tl[r][tx] = ip[(size_t)r * N + tx];
  }
  __syncthreads();
  short* op = (short*)out + (size_t)(bj * 32) * K + bi * 32;
#pragma unroll
  for (int r0 = 0; r0 < 4; ++r0) {
    int r = ty + r0 * 8;
    op[(size_t)r * K + tx] = f2bf(tl[tx][r]);
  }
}

__global__ __launch_bounds__(256) void prep_kernel(const float* __restrict__ x,
                                                   bf16* __restrict__ xbf,
                                                   const float* __restrict__ Wa,
                                                   bf16* __restrict__ WaT,
                                                   const float* __restrict__ Wp,
                                                   bf16* __restrict__ WpT) {
  const int bid = blockIdx.x, tid = threadIdx.x;
  if (bid < 4096) {
    const int i = bid * 256 + tid;
    const float* ip = x + (size_t)i * 8;
    f32x4v f0 = ((const f32x4v*)ip)[0];
    f32x4v f1 = ((const f32x4v*)ip)[1];
    bf16x8 o;
#pragma unroll
    for (int j = 0; j < 4; ++j) { o[j] = f2bf(f0[j]); o[4 + j] = f2bf(f1[j]); }
    *(bf16x8*)((short*)xbf + (size_t)i * 8) = o;
  } else if (bid < 7168) {
    const int b = bid - 4096;
    wtrans_body(Wa, WaT, CC, N1, b % 96, b / 96, tid);
  } else {
    const int b = bid - 7168;
    wtrans_body(Wp, WpT, CC, CC, b % 32, b / 32, tid);
  }
}

// ---------------- GEMM1: qkv = xb(bf16) @ WaT^T, scatter to q/k/v bf16 -------
// BK=64 XOR-swizzled tiles (pre-swizzled global source + linear gload_lds
// dest + XOR on fragment reads).
__global__ __launch_bounds__(256) void gemm_qkv_kernel(const bf16* __restrict__ xb,
                                                       const bf16* __restrict__ WaT,
                                                       bf16* __restrict__ qb,
                                                       bf16* __restrict__ kb,
                                                       bf16* __restrict__ vb) {
  __shared__ bf16 As[128 * 64];
  __shared__ bf16 Bs[128 * 64];
  const int tid = threadIdx.x;
  const int wid = tid >> 6, lane = tid & 63, row16 = lane & 15, g = lane >> 4;
  const int wr = wid >> 1, wc = wid & 1;
  const int mbase = blockIdx.x * 128, nbase = blockIdx.y * 128;

  f32x4 acc[4][4] = {};

  for (int kt = 0; kt < CC; kt += 64) {
#pragma unroll
    for (int i = 0; i < 4; ++i) {
      int chunk = i * 256 + tid;                       // 0..1023
      int row = chunk >> 3;                            // 0..127
      int cb = ((chunk & 7) * 16) ^ ((row & 7) << 4);  // swizzled col byte
      gload_lds16((const char*)(xb + (size_t)(mbase + row) * CC + kt) + cb,
                  (char*)As + chunk * 16);
      gload_lds16((const char*)(WaT + (size_t)(nbase + row) * CC + kt) + cb,
                  (char*)Bs + chunk * 16);
    }
    __syncthreads();
#pragma unroll
    for (int kk = 0; kk < 2; ++kk) {
      bf16x8 af[4], bfr[4];
#pragma unroll
      for (int m = 0; m < 4; ++m) {
        int row = wr * 64 + m * 16 + row16;
        af[m] = *(const bf16x8*)((char*)As +
                 ((row * 128 + kk * 64 + g * 16) ^ ((row & 7) << 4)));
      }
#pragma unroll
      for (int n = 0; n < 4; ++n) {
        int row = wc * 64 + n * 16 + row16;
        bfr[n] = *(const bf16x8*)((char*)Bs +
                 ((row * 128 + kk * 64 + g * 16) ^ ((row & 7) << 4)));
      }
#pragma unroll
      for (int m = 0; m < 4; ++m)
#pragma unroll
        for (int n = 0; n < 4; ++n)
          acc[m][n] = __builtin_amdgcn_mfma_f32_16x16x32_bf16(af[m], bfr[n], acc[m][n], 0, 0, 0);
    }
    __syncthreads();
  }
  // epilogue: scatter to q/k/v (B,H,T,HD) bf16
#pragma unroll
  for (int m = 0; m < 4; ++m) {
    int grow0 = mbase + wr * 64 + m * 16 + g * 4;
#pragma unroll
    for (int n = 0; n < 4; ++n) {
      int gcol = nbase + wc * 64 + n * 16 + row16;
      int which = gcol >> 10, c = gcol & 1023, h = c >> 6, d = c & 63;
      short* dst = (short*)(which == 0 ? qb : (which == 1 ? kb : vb));
      float sc = (which == 0) ? 0.18033688011112042f : 1.0f;  // 0.125 * log2(e)
#pragma unroll
      for (int r = 0; r < 4; ++r) {
        int rr = grow0 + r;
        int b = rr >> 11, t = rr & 2047;
        dst[(((size_t)(b * HH + h)) * TT + t) * HD + d] = f2bf(acc[m][n][r] * sc);
      }
    }
  }
}

// ---------------- flash attention: round-13 base + ones-MFMA l --------------
// hi/lo paired 128-row q-tiles, swapped QK^T (S^T=K*Q), fixed-shift exp2
// softmax (log2e folded into Q), raw v_exp_f32, LDS-P K=32 PV, K/V dbuf,
// pair-CU mixing. Single change: l accumulated via ones-column MFMA on the
// P fragments (C = P @ 1 lands l[q] in the O-acc row layout) -- removes
// 64 VALU adds/wave-tile and ALL finalize shuffles.
__global__ __launch_bounds__(256, 2) void attn_kernel(const bf16* __restrict__ qb,
                                                      const bf16* __restrict__ kb,
                                                      const bf16* __restrict__ vb,
                                                      bf16* __restrict__ yb) {
  // LDS: K dbuf 2x8KB | V^T dbuf 2x8KB | P per-wave 4x8KB  = 64KB
  __shared__ __align__(16) char smem[65536];
  const int tid = threadIdx.x, wid = tid >> 6, lane = tid & 63;
  const int row16 = lane & 15, g = lane >> 4;
  const int bh = blockIdx.y;
  const int pair = (blockIdx.x + (bh >> 3)) & 7;
  const int Qlo = pair, Qhi = 15 - pair;
  const size_t hbase = (size_t)bh * TT * HD;
  const bf16* qh = qb + hbase;
  const char* kh = (const char*)(kb + hbase);
  const char* vh = (const char*)(vb + hbase);

  const int hq0 = Qhi * 128 + wid * 32;   // wave's first hi q row (global)
  const int lq0 = Qlo * 128 + wid * 32;   // wave's first lo q row (global)
  const int nt   = 2 * Qhi + 2;
  const int hcap = 2 * Qhi + (wid >> 1) + 1;  // hi active iff kt < hcap
  const int lcap = 2 * Qlo + (wid >> 1) + 1;  // lo active iff kt < lcap

  // Q B-fragments: col=q=lane&15, k=d contiguous (scale*log2e pre-folded)
  bf16x8 qfh[2][2], qfl[2][2];
#pragma unroll
  for (int m = 0; m < 2; ++m)
#pragma unroll
    for (int kk = 0; kk < 2; ++kk) {
      qfh[m][kk] = *(const bf16x8*)(qh + (size_t)(hq0 + m * 16 + row16) * HD + kk * 32 + g * 8);
      qfl[m][kk] = *(const bf16x8*)(qh + (size_t)(lq0 + m * 16 + row16) * HD + kk * 32 + g * 8);
    }

  f32x4 acch[2][4] = {}, accl[2][4] = {};   // O rows g*4+r, cols row16
  f32x4 accLh[2] = {}, accLl[2] = {};       // l rows g*4+r (all cols equal)
  bf16x8 ones;
#pragma unroll
  for (int j = 0; j < 8; ++j) ones[j] = (short)0x3F80;  // bf16 1.0

  const int vkv0 = (tid >> 3) * 2, vd0 = (tid & 7) * 8;
  char* pw = smem + 32768 + wid * 8192;    // hi set at pw, lo set at pw+4096

  // prologue: stage tile 0 into buffer 0
  {
#pragma unroll
    for (int i = 0; i < 2; ++i) {
      int chunk = i * 256 + tid;
      int r = chunk >> 3;
      int cb = ((chunk & 7) * 16) ^ ((r & 7) << 4);
      gload_lds16(kh + (size_t)r * 128 + cb, smem + chunk * 16);
    }
    const char* vsrc = vh + (size_t)vkv0 * 128 + vd0 * 2;
    bf16x8 r0 = *(const bf16x8*)vsrc;
    bf16x8 r1 = *(const bf16x8*)(vsrc + 128);
    char* vdst = smem + 16384;
#pragma unroll
    for (int j = 0; j < 8; ++j) {
      int d = vd0 + j;
      uint32_t val = (uint32_t)(uint16_t)r0[j] | ((uint32_t)(uint16_t)r1[j] << 16);
      *(uint32_t*)(vdst + ((d * 128 + vkv0 * 2) ^ (((d + (d >> 3)) & 7) << 4))) = val;
    }
  }
  __syncthreads();

  for (int kt = 0; kt < nt; ++kt) {
    const int cur = kt & 1;
    char* kc = smem + cur * 8192;
    char* vc = smem + 16384 + cur * 8192;
    const bool havenext = (kt + 1 < nt);
    bf16x8 vr0, vr1;
    if (havenext) {
      char* kn = smem + (1 - cur) * 8192;
#pragma unroll
      for (int i = 0; i < 2; ++i) {
        int chunk = i * 256 + tid;
        int r = chunk >> 3;
        int cb = ((chunk & 7) * 16) ^ ((r & 7) << 4);
        gload_lds16(kh + (size_t)((kt + 1) * 64 + r) * 128 + cb, kn + chunk * 16);
      }
      const char* vsrc = vh + (size_t)((kt + 1) * 64 + vkv0) * 128 + vd0 * 2;
      vr0 = *(const bf16x8*)vsrc;
      vr1 = *(const bf16x8*)(vsrc + 128);
    }

    const bool hA = kt < hcap, lA = kt < lcap;
    if (hA | lA) {
      const bool maskh = (kt * 64 + 63) > hq0;
      const bool maskl = (kt * 64 + 63) > lq0;
      // S^T = K*Q per 16-kv chunk c, for both q-sets; exp2 + pack + P store
#pragma unroll
      for (int c = 0; c < 4; ++c) {
        int krow = c * 16 + row16;
        int ksw = (krow & 7) << 4;
        bf16x8 kf0 = *(const bf16x8*)(kc + ((krow * 128 + g * 16) ^ ksw));
        bf16x8 kf1 = *(const bf16x8*)(kc + ((krow * 128 + 64 + g * 16) ^ ksw));
        if (hA) {
#pragma unroll
          for (int m = 0; m < 2; ++m) {
            f32x4 st = {};
            st = __builtin_amdgcn_mfma_f32_16x16x32_bf16(kf0, qfh[m][0], st, 0, 0, 0);
            st = __builtin_amdgcn_mfma_f32_16x16x32_bf16(kf1, qfh[m][1], st, 0, 0, 0);
            const int thr = hq0 + m * 16 + row16 - kt * 64;
            float pv[4];
#pragma unroll
            for (int r = 0; r < 4; ++r) {
              float pe = __builtin_amdgcn_exp2f(st[r]);
              if (maskh) pe = (c * 16 + g * 4 + r > thr) ? 0.f : pe;
              pv[r] = pe;
            }
            u32x2 w;
            w[0] = cvt_pk_bf16(pv[0], pv[1]);
            w[1] = cvt_pk_bf16(pv[2], pv[3]);
            int prow = m * 16 + row16;
            *(u32x2*)(pw + ((prow * 128 + c * 32 + g * 8) ^ ((row16 & 7) << 4))) = w;
          }
        }
        if (lA) {
#pragma unroll
          for (int m = 0; m < 2; ++m) {
            f32x4 st = {};
            st = __builtin_amdgcn_mfma_f32_16x16x32_bf16(kf0, qfl[m][0], st, 0, 0, 0);
            st = __builtin_amdgcn_mfma_f32_16x16x32_bf16(kf1, qfl[m][1], st, 0, 0, 0);
            const int thr = lq0 + m * 16 + row16 - kt * 64;
            float pv[4];
#pragma unroll
            for (int r = 0; r < 4; ++r) {
              float pe = __builtin_amdgcn_exp2f(st[r]);
              if (maskl) pe = (c * 16 + g * 4 + r > thr) ? 0.f : pe;
              pv[r] = pe;
            }
            u32x2 w;
            w[0] = cvt_pk_bf16(pv[0], pv[1]);
            w[1] = cvt_pk_bf16(pv[2], pv[3]);
            int prow = m * 16 + row16;
            *(u32x2*)(pw + 4096 + ((prow * 128 + c * 32 + g * 8) ^ ((row16 & 7) << 4))) = w;
          }
        }
      }
      // P fragments (A-operand: contiguous kv per lane)
      bf16x8 pah[2][2], pal[2][2];
#pragma unroll
      for (int m = 0; m < 2; ++m) {
        int prow = m * 16 + row16;
        int psw = (row16 & 7) << 4;
#pragma unroll
        for (int kk = 0; kk < 2; ++kk) {
          if (hA) pah[m][kk] = *(const bf16x8*)(pw + ((prow * 128 + kk * 64 + g * 16) ^ psw));
          if (lA) pal[m][kk] = *(const bf16x8*)(pw + 4096 + ((prow * 128 + kk * 64 + g * 16) ^ psw));
        }
      }
      __builtin_amdgcn_s_setprio(1);
      // l = P @ 1 on the MFMA pipe (C rows == O-acc rows, no shuffles later)
      if (hA) {
#pragma unroll
        for (int m = 0; m < 2; ++m) {
          accLh[m] = __builtin_amdgcn_mfma_f32_16x16x32_bf16(pah[m][0], ones, accLh[m], 0, 0, 0);
          accLh[m] = __builtin_amdgcn_mfma_f32_16x16x32_bf16(pah[m][1], ones, accLh[m], 0, 0, 0);
        }
      }
      if (lA) {
#pragma unroll
        for (int m = 0; m < 2; ++m) {
          accLl[m] = __builtin_amdgcn_mfma_f32_16x16x32_bf16(pal[m][0], ones, accLl[m], 0, 0, 0);
          accLl[m] = __builtin_amdgcn_mfma_f32_16x16x32_bf16(pal[m][1], ones, accLl[m], 0, 0, 0);
        }
      }
      // PV for both sets, shared V fragments
#pragma unroll
      for (int nd = 0; nd < 4; ++nd) {
        int vrow = nd * 16 + row16;
        int vsw = ((vrow + (vrow >> 3)) & 7) << 4;
        bf16x8 vf0 = *(const bf16x8*)(vc + ((vrow * 128 + g * 16) ^ vsw));
        bf16x8 vf1 = *(const bf16x8*)(vc + ((vrow * 128 + 64 + g * 16) ^ vsw));
        if (hA) {
#pragma unroll
          for (int m = 0; m < 2; ++m) {
            acch[m][nd] = __builtin_amdgcn_mfma_f32_16x16x32_bf16(pah[m][0], vf0, acch[m][nd], 0, 0, 0);
            acch[m][nd] = __builtin_amdgcn_mfma_f32_16x16x32_bf16(pah[m][1], vf1, acch[m][nd], 0, 0, 0);
          }
        }
        if (lA) {
#pragma unroll
          for (int m = 0; m < 2; ++m) {
            accl[m][nd] = __builtin_amdgcn_mfma_f32_16x16x32_bf16(pal[m][0], vf0, accl[m][nd], 0, 0, 0);
            accl[m][nd] = __builtin_amdgcn_mfma_f32_16x16x32_bf16(pal[m][1], vf1, accl[m][nd], 0, 0, 0);
          }
        }
      }
      __builtin_amdgcn_s_setprio(0);
    }

    if (havenext) {
      char* vn = smem + 16384 + (1 - cur) * 8192;
#pragma unroll
      for (int j = 0; j < 8; ++j) {
        int d = vd0 + j;
        uint32_t val = (uint32_t)(uint16_t)vr0[j] | ((uint32_t)(uint16_t)vr1[j] << 16);
        *(uint32_t*)(vn + ((d * 128 + vkv0 * 2) ^ (((d + (d >> 3)) & 7) << 4))) = val;
      }
    }
    __syncthreads();
  }

  // finalize: l already per-row in accL (same row layout as acc)
  const int b = bh >> 4, h = bh & 15;
#pragma unroll
  for (int m = 0; m < 2; ++m)
#pragma unroll
    for (int r = 0; r < 4; ++r) {
      float lih = __builtin_amdgcn_rcpf(accLh[m][r]);
      float lil = __builtin_amdgcn_rcpf(accLl[m][r]);
      int th = hq0 + m * 16 + g * 4 + r;
      int tl = lq0 + m * 16 + g * 4 + r;
#pragma unroll
      for (int nd = 0; nd < 4; ++nd) {
        ((short*)yb)[((size_t)(b * TT + th)) * CC + h * HD + nd * 16 + row16] =
            f2bf(acch[m][nd][r] * lih);
        ((short*)yb)[((size_t)(b * TT + tl)) * CC + h * HD + nd * 16 + row16] =
            f2bf(accl[m][nd][r] * lil);
      }
    }
}

// ---------------- GEMM2: out(fp32) = y(bf16) @ WpT^T, BK=64 -----------------
__global__ __launch_bounds__(256) void gemm_proj_kernel(const bf16* __restrict__ yb,
                                                        const bf16* __restrict__ WpT,
                                                        float* __restrict__ out) {
  __shared__ bf16 As[128 * 64];
  __shared__ bf16 Bs[128 * 64];
  const int tid = threadIdx.x;
  const int wid = tid >> 6, lane = tid & 63, row16 = lane & 15, g = lane >> 4;
  const int wr = wid >> 1, wc = wid & 1;
  const int mbase = blockIdx.x * 128, nbase = blockIdx.y * 128;

  f32x4 acc[4][4] = {};

  for (int kt = 0; kt < CC; kt += 64) {
#pragma unroll
    for (int i = 0; i < 4; ++i) {
      int chunk = i * 256 + tid;
      int row = chunk >> 3;
      int cb = ((chunk & 7) * 16) ^ ((row & 7) << 4);
      gload_lds16((const char*)(yb + (size_t)(mbase + row) * CC + kt) + cb,
                  (char*)As + chunk * 16);
      gload_lds16((const char*)(WpT + (size_t)(nbase + row) * CC + kt) + cb,
                  (char*)Bs + chunk * 16);
    }
    __syncthreads();
#pragma unroll
    for (int kk = 0; kk < 2; ++kk) {
      bf16x8 af[4], bfr[4];
#pragma unroll
      for (int m = 0; m < 4; ++m) {
        int row = wr * 64 + m * 16 + row16;
        af[m] = *(const bf16x8*)((char*)As +
                 ((row * 128 + kk * 64 + g * 16) ^ ((row & 7) << 4)));
      }
#pragma unroll
      for (int n = 0; n < 4; ++n) {
        int row = wc * 64 + n * 16 + row16;
        bfr[n] = *(const bf16x8*)((char*)Bs +
                 ((row * 128 + kk * 64 + g * 16) ^ ((row & 7) << 4)));
      }
#pragma unroll
      for (int m = 0; m < 4; ++m)
#pragma unroll
        for (int n = 0; n < 4; ++n)
          acc[m][n] = __builtin_amdgcn_mfma_f32_16x16x32_bf16(af[m], bfr[n], acc[m][n], 0, 0, 0);
    }
    __syncthreads();
  }
#pragma unroll
  for (int m = 0; m < 4; ++m) {
    int grow0 = mbase + wr * 64 + m * 16 + g * 4;
#pragma unroll
    for (int n = 0; n < 4; ++n) {
      int gcol = nbase + wc * 64 + n * 16 + row16;
#pragma unroll
      for (int r = 0; r < 4; ++r)
        out[(size_t)(grow0 + r) * CC + gcol] = acc[m][n][r];
    }
  }
}

// ---------------- launch ----------------------------------------------------
extern "C" void kernel_launch(void* const* d_in, const int* in_sizes, int n_in,
                              void* d_out, int out_size, void* d_ws, size_t ws_size,
                              hipStream_t stream) {
  const float* x      = (const float*)d_in[0];
  const float* W_attn = (const float*)d_in[1];
  const float* W_proj = (const float*)d_in[2];
  float* out = (float*)d_out;

  char* ws = (char*)d_ws;
  // layout: WaT 6MB | WpT 2MB | q 16MB | k 16MB | v 16MB | y 16MB (= 72MB)
  // x_bf (16MB) ALIASES the y region: x_bf is dead before attn writes y.
  bf16* WaT = (bf16*)(ws);
  bf16* WpT = (bf16*)(ws + 6291456);
  bf16* qb  = (bf16*)(ws + 8388608);
  bf16* kb  = (bf16*)(ws + 8388608 + 16777216);
  bf16* vb  = (bf16*)(ws + 8388608 + 2 * 16777216);
  bf16* yb  = (bf16*)(ws + 8388608 + 3 * 16777216);
  bf16* xbf = yb;

  prep_kernel<<<dim3(8192), 256, 0, stream>>>(x, xbf, W_attn, WaT, W_proj, WpT);
  gemm_qkv_kernel<<<dim3(MM / 128, N1 / 128), 256, 0, stream>>>(xbf, WaT, qb, kb, vb);
  attn_kernel<<<dim3(8, BB * HH), 256, 0, stream>>>(qb, kb, vb, yb);
  gemm_proj_kernel<<<dim3(MM / 128, CC / 128), 256, 0, stream>>>(yb, WpT, out);
}

// Round 16
// 168.417 us; speedup vs baseline: 1.0187x; 1.0187x over previous
//
#include <hip/hip_runtime.h>
#include <hip/hip_bf16.h>
#include <stdint.h>

// Problem constants: B=4, T=2048, C=1024, H=16, HD=64
#define BB 4
#define TT 2048
#define CC 1024
#define HH 16
#define HD 64
#define MM (BB*TT)      /* 8192 */
#define N1 (3*CC)       /* 3072 */

typedef short bf16x8 __attribute__((ext_vector_type(8)));
typedef float f32x4  __attribute__((ext_vector_type(4)));
typedef float f32x4v __attribute__((ext_vector_type(4)));
typedef uint32_t u32x2 __attribute__((ext_vector_type(2)));

using bf16 = __hip_bfloat16;

static __device__ __forceinline__ short f2bf(float f) {
  union { float f; uint32_t u; } v; v.f = f;
  uint32_t u = v.u;
  u += 0x7fffu + ((u >> 16) & 1u);
  return (short)(u >> 16);
}

static __device__ __forceinline__ uint32_t cvt_pk_bf16(float lo, float hi) {
  uint32_t r;
  asm("v_cvt_pk_bf16_f32 %0, %1, %2" : "=v"(r) : "v"(lo), "v"(hi));
  return r;
}

static __device__ __forceinline__ void gload_lds16(const void* g, void* l) {
  __builtin_amdgcn_global_load_lds(
      (const __attribute__((address_space(1))) uint32_t*)g,
      (__attribute__((address_space(3))) uint32_t*)l, 16, 0, 0);
}

// ---------------- prep: xcast + both weight transposes, one launch ----------
static __device__ __forceinline__ void wtrans_body(const float* __restrict__ in,
                                                   bf16* __restrict__ out,
                                                   int K, int N, int bj, int bi,
                                                   int tid) {
  __shared__ float tl[32][33];
  const int tx = tid & 31, ty = tid >> 5;
  const float* ip = in + (size_t)(bi * 32) * N + bj * 32;
#pragma unroll
  for (int r0 = 0; r0 < 4; ++r0) {
    int r = ty + r0 * 8;
    tl[r][tx] = ip[(size_t)r * N + tx];
  }
  __syncthreads();
  short* op = (short*)out + (size_t)(bj * 32) * K + bi * 32;
#pragma unroll
  for (int r0 = 0; r0 < 4; ++r0) {
    int r = ty + r0 * 8;
    op[(size_t)r * K + tx] = f2bf(tl[tx][r]);
  }
}

__global__ __launch_bounds__(256) void prep_kernel(const float* __restrict__ x,
                                                   bf16* __restrict__ xbf,
                                                   const float* __restrict__ Wa,
                                                   bf16* __restrict__ WaT,
                                                   const float* __restrict__ Wp,
                                                   bf16* __restrict__ WpT) {
  const int bid = blockIdx.x, tid = threadIdx.x;
  if (bid < 4096) {
    const int i = bid * 256 + tid;
    const float* ip = x + (size_t)i * 8;
    f32x4v f0 = ((const f32x4v*)ip)[0];
    f32x4v f1 = ((const f32x4v*)ip)[1];
    bf16x8 o;
#pragma unroll
    for (int j = 0; j < 4; ++j) { o[j] = f2bf(f0[j]); o[4 + j] = f2bf(f1[j]); }
    *(bf16x8*)((short*)xbf + (size_t)i * 8) = o;
  } else if (bid < 7168) {
    const int b = bid - 4096;
    wtrans_body(Wa, WaT, CC, N1, b % 96, b / 96, tid);
  } else {
    const int b = bid - 7168;
    wtrans_body(Wp, WpT, CC, CC, b % 32, b / 32, tid);
  }
}

// ---------------- GEMM1: qkv = xb(bf16) @ WaT^T, scatter to q/k/v bf16 -------
// BK=64 (16 K-iterations, half the barrier drains of BK=32). Tiles stored
// XOR-swizzled (pre-swizzled global source + linear gload_lds dest + XOR on
// fragment reads) -- same proven pattern as attn's K staging (128B rows).
__global__ __launch_bounds__(256) void gemm_qkv_kernel(const bf16* __restrict__ xb,
                                                       const bf16* __restrict__ WaT,
                                                       bf16* __restrict__ qb,
                                                       bf16* __restrict__ kb,
                                                       bf16* __restrict__ vb) {
  __shared__ bf16 As[128 * 64];
  __shared__ bf16 Bs[128 * 64];
  const int tid = threadIdx.x;
  const int wid = tid >> 6, lane = tid & 63, row16 = lane & 15, g = lane >> 4;
  const int wr = wid >> 1, wc = wid & 1;
  const int mbase = blockIdx.x * 128, nbase = blockIdx.y * 128;

  f32x4 acc[4][4] = {};

  for (int kt = 0; kt < CC; kt += 64) {
#pragma unroll
    for (int i = 0; i < 4; ++i) {
      int chunk = i * 256 + tid;                       // 0..1023
      int row = chunk >> 3;                            // 0..127
      int cb = ((chunk & 7) * 16) ^ ((row & 7) << 4);  // swizzled col byte
      gload_lds16((const char*)(xb + (size_t)(mbase + row) * CC + kt) + cb,
                  (char*)As + chunk * 16);
      gload_lds16((const char*)(WaT + (size_t)(nbase + row) * CC + kt) + cb,
                  (char*)Bs + chunk * 16);
    }
    __syncthreads();
#pragma unroll
    for (int kk = 0; kk < 2; ++kk) {
      bf16x8 af[4], bfr[4];
#pragma unroll
      for (int m = 0; m < 4; ++m) {
        int row = wr * 64 + m * 16 + row16;
        af[m] = *(const bf16x8*)((char*)As +
                 ((row * 128 + kk * 64 + g * 16) ^ ((row & 7) << 4)));
      }
#pragma unroll
      for (int n = 0; n < 4; ++n) {
        int row = wc * 64 + n * 16 + row16;
        bfr[n] = *(const bf16x8*)((char*)Bs +
                 ((row * 128 + kk * 64 + g * 16) ^ ((row & 7) << 4)));
      }
#pragma unroll
      for (int m = 0; m < 4; ++m)
#pragma unroll
        for (int n = 0; n < 4; ++n)
          acc[m][n] = __builtin_amdgcn_mfma_f32_16x16x32_bf16(af[m], bfr[n], acc[m][n], 0, 0, 0);
    }
    __syncthreads();
  }
  // epilogue: scatter to q/k/v (B,H,T,HD) bf16
#pragma unroll
  for (int m = 0; m < 4; ++m) {
    int grow0 = mbase + wr * 64 + m * 16 + g * 4;
#pragma unroll
    for (int n = 0; n < 4; ++n) {
      int gcol = nbase + wc * 64 + n * 16 + row16;
      int which = gcol >> 10, c = gcol & 1023, h = c >> 6, d = c & 63;
      short* dst = (short*)(which == 0 ? qb : (which == 1 ? kb : vb));
      float sc = (which == 0) ? 0.18033688011112042f : 1.0f;  // 0.125 * log2(e)
#pragma unroll
      for (int r = 0; r < 4; ++r) {
        int rr = grow0 + r;
        int b = rr >> 11, t = rr & 2047;
        dst[(((size_t)(b * HH + h)) * TT + t) * HD + d] = f2bf(acc[m][n][r] * sc);
      }
    }
  }
}

// ---------------- flash attention (round-14 verified best) ------------------
// hi/lo paired 128-row q-tiles, swapped QK^T (S^T=K*Q), fixed-shift exp2
// softmax (log2e folded into Q), raw v_exp_f32, LDS-P K=32 PV, K/V dbuf,
// pair-CU mixing: pair = (blockIdx.x + (blockIdx.y>>3)) & 7.
__global__ __launch_bounds__(256, 2) void attn_kernel(const bf16* __restrict__ qb,
                                                      const bf16* __restrict__ kb,
                                                      const bf16* __restrict__ vb,
                                                      bf16* __restrict__ yb) {
  // LDS: K dbuf 2x8KB | V^T dbuf 2x8KB | P per-wave 4x8KB  = 64KB
  __shared__ __align__(16) char smem[65536];
  const int tid = threadIdx.x, wid = tid >> 6, lane = tid & 63;
  const int row16 = lane & 15, g = lane >> 4;
  const int bh = blockIdx.y;
  const int pair = (blockIdx.x + (bh >> 3)) & 7;
  const int Qlo = pair, Qhi = 15 - pair;
  const size_t hbase = (size_t)bh * TT * HD;
  const bf16* qh = qb + hbase;
  const char* kh = (const char*)(kb + hbase);
  const char* vh = (const char*)(vb + hbase);

  const int hq0 = Qhi * 128 + wid * 32;   // wave's first hi q row (global)
  const int lq0 = Qlo * 128 + wid * 32;   // wave's first lo q row (global)
  const int nt   = 2 * Qhi + 2;
  const int hcap = 2 * Qhi + (wid >> 1) + 1;  // hi active iff kt < hcap
  const int lcap = 2 * Qlo + (wid >> 1) + 1;  // lo active iff kt < lcap

  // Q B-fragments: col=q=lane&15, k=d contiguous (scale*log2e pre-folded)
  bf16x8 qfh[2][2], qfl[2][2];
#pragma unroll
  for (int m = 0; m < 2; ++m)
#pragma unroll
    for (int kk = 0; kk < 2; ++kk) {
      qfh[m][kk] = *(const bf16x8*)(qh + (size_t)(hq0 + m * 16 + row16) * HD + kk * 32 + g * 8);
      qfl[m][kk] = *(const bf16x8*)(qh + (size_t)(lq0 + m * 16 + row16) * HD + kk * 32 + g * 8);
    }

  f32x4 acch[2][4] = {}, accl[2][4] = {};   // O rows g*4+r, cols row16
  float lph[2] = {0.f, 0.f}, lpl[2] = {0.f, 0.f};

  const int vkv0 = (tid >> 3) * 2, vd0 = (tid & 7) * 8;
  char* pw = smem + 32768 + wid * 8192;    // hi set at pw, lo set at pw+4096

  // prologue: stage tile 0 into buffer 0
  {
#pragma unroll
    for (int i = 0; i < 2; ++i) {
      int chunk = i * 256 + tid;
      int r = chunk >> 3;
      int cb = ((chunk & 7) * 16) ^ ((r & 7) << 4);
      gload_lds16(kh + (size_t)r * 128 + cb, smem + chunk * 16);
    }
    const char* vsrc = vh + (size_t)vkv0 * 128 + vd0 * 2;
    bf16x8 r0 = *(const bf16x8*)vsrc;
    bf16x8 r1 = *(const bf16x8*)(vsrc + 128);
    char* vdst = smem + 16384;
#pragma unroll
    for (int j = 0; j < 8; ++j) {
      int d = vd0 + j;
      uint32_t val = (uint32_t)(uint16_t)r0[j] | ((uint32_t)(uint16_t)r1[j] << 16);
      *(uint32_t*)(vdst + ((d * 128 + vkv0 * 2) ^ (((d + (d >> 3)) & 7) << 4))) = val;
    }
  }
  __syncthreads();

  for (int kt = 0; kt < nt; ++kt) {
    const int cur = kt & 1;
    char* kc = smem + cur * 8192;
    char* vc = smem + 16384 + cur * 8192;
    const bool havenext = (kt + 1 < nt);
    bf16x8 vr0, vr1;
    if (havenext) {
      char* kn = smem + (1 - cur) * 8192;
#pragma unroll
      for (int i = 0; i < 2; ++i) {
        int chunk = i * 256 + tid;
        int r = chunk >> 3;
        int cb = ((chunk & 7) * 16) ^ ((r & 7) << 4);
        gload_lds16(kh + (size_t)((kt + 1) * 64 + r) * 128 + cb, kn + chunk * 16);
      }
      const char* vsrc = vh + (size_t)((kt + 1) * 64 + vkv0) * 128 + vd0 * 2;
      vr0 = *(const bf16x8*)vsrc;
      vr1 = *(const bf16x8*)(vsrc + 128);
    }

    const bool hA = kt < hcap, lA = kt < lcap;
    if (hA | lA) {
      const bool maskh = (kt * 64 + 63) > hq0;
      const bool maskl = (kt * 64 + 63) > lq0;
      // S^T = K*Q per 16-kv chunk c, for both q-sets; exp2 + pack + P store
#pragma unroll
      for (int c = 0; c < 4; ++c) {
        int krow = c * 16 + row16;
        int ksw = (krow & 7) << 4;
        bf16x8 kf0 = *(const bf16x8*)(kc + ((krow * 128 + g * 16) ^ ksw));
        bf16x8 kf1 = *(const bf16x8*)(kc + ((krow * 128 + 64 + g * 16) ^ ksw));
        if (hA) {
#pragma unroll
          for (int m = 0; m < 2; ++m) {
            f32x4 st = {};
            st = __builtin_amdgcn_mfma_f32_16x16x32_bf16(kf0, qfh[m][0], st, 0, 0, 0);
            st = __builtin_amdgcn_mfma_f32_16x16x32_bf16(kf1, qfh[m][1], st, 0, 0, 0);
            const int thr = hq0 + m * 16 + row16 - kt * 64;
            float pv[4];
#pragma unroll
            for (int r = 0; r < 4; ++r) {
              float pe = __builtin_amdgcn_exp2f(st[r]);
              if (maskh) pe = (c * 16 + g * 4 + r > thr) ? 0.f : pe;
              pv[r] = pe;
              lph[m] += pe;
            }
            u32x2 w;
            w[0] = cvt_pk_bf16(pv[0], pv[1]);
            w[1] = cvt_pk_bf16(pv[2], pv[3]);
            int prow = m * 16 + row16;
            *(u32x2*)(pw + ((prow * 128 + c * 32 + g * 8) ^ ((row16 & 7) << 4))) = w;
          }
        }
        if (lA) {
#pragma unroll
          for (int m = 0; m < 2; ++m) {
            f32x4 st = {};
            st = __builtin_amdgcn_mfma_f32_16x16x32_bf16(kf0, qfl[m][0], st, 0, 0, 0);
            st = __builtin_amdgcn_mfma_f32_16x16x32_bf16(kf1, qfl[m][1], st, 0, 0, 0);
            const int thr = lq0 + m * 16 + row16 - kt * 64;
            float pv[4];
#pragma unroll
            for (int r = 0; r < 4; ++r) {
              float pe = __builtin_amdgcn_exp2f(st[r]);
              if (maskl) pe = (c * 16 + g * 4 + r > thr) ? 0.f : pe;
              pv[r] = pe;
              lpl[m] += pe;
            }
            u32x2 w;
            w[0] = cvt_pk_bf16(pv[0], pv[1]);
            w[1] = cvt_pk_bf16(pv[2], pv[3]);
            int prow = m * 16 + row16;
            *(u32x2*)(pw + 4096 + ((prow * 128 + c * 32 + g * 8) ^ ((row16 & 7) << 4))) = w;
          }
        }
      }
      // P fragments (A-operand: contiguous kv per lane)
      bf16x8 pah[2][2], pal[2][2];
#pragma unroll
      for (int m = 0; m < 2; ++m) {
        int prow = m * 16 + row16;
        int psw = (row16 & 7) << 4;
#pragma unroll
        for (int kk = 0; kk < 2; ++kk) {
          if (hA) pah[m][kk] = *(const bf16x8*)(pw + ((prow * 128 + kk * 64 + g * 16) ^ psw));
          if (lA) pal[m][kk] = *(const bf16x8*)(pw + 4096 + ((prow * 128 + kk * 64 + g * 16) ^ psw));
        }
      }
      // PV for both sets, shared V fragments
      __builtin_amdgcn_s_setprio(1);
#pragma unroll
      for (int nd = 0; nd < 4; ++nd) {
        int vrow = nd * 16 + row16;
        int vsw = ((vrow + (vrow >> 3)) & 7) << 4;
        bf16x8 vf0 = *(const bf16x8*)(vc + ((vrow * 128 + g * 16) ^ vsw));
        bf16x8 vf1 = *(const bf16x8*)(vc + ((vrow * 128 + 64 + g * 16) ^ vsw));
        if (hA) {
#pragma unroll
          for (int m = 0; m < 2; ++m) {
            acch[m][nd] = __builtin_amdgcn_mfma_f32_16x16x32_bf16(pah[m][0], vf0, acch[m][nd], 0, 0, 0);
            acch[m][nd] = __builtin_amdgcn_mfma_f32_16x16x32_bf16(pah[m][1], vf1, acch[m][nd], 0, 0, 0);
          }
        }
        if (lA) {
#pragma unroll
          for (int m = 0; m < 2; ++m) {
            accl[m][nd] = __builtin_amdgcn_mfma_f32_16x16x32_bf16(pal[m][0], vf0, accl[m][nd], 0, 0, 0);
            accl[m][nd] = __builtin_amdgcn_mfma_f32_16x16x32_bf16(pal[m][1], vf1, accl[m][nd], 0, 0, 0);
          }
        }
      }
      __builtin_amdgcn_s_setprio(0);
    }

    if (havenext) {
      char* vn = smem + 16384 + (1 - cur) * 8192;
#pragma unroll
      for (int j = 0; j < 8; ++j) {
        int d = vd0 + j;
        uint32_t val = (uint32_t)(uint16_t)vr0[j] | ((uint32_t)(uint16_t)vr1[j] << 16);
        *(uint32_t*)(vn + ((d * 128 + vkv0 * 2) ^ (((d + (d >> 3)) & 7) << 4))) = val;
      }
    }
    __syncthreads();
  }

  // finalize: reduce l across g-groups; fetch per-acc-row l via shuffle
  const int b = bh >> 4, h = bh & 15;
#pragma unroll
  for (int m = 0; m < 2; ++m) {
    lph[m] += __shfl_xor(lph[m], 16); lph[m] += __shfl_xor(lph[m], 32);
    lpl[m] += __shfl_xor(lpl[m], 16); lpl[m] += __shfl_xor(lpl[m], 32);
  }
#pragma unroll
  for (int m = 0; m < 2; ++m)
#pragma unroll
    for (int r = 0; r < 4; ++r) {
      int srcl = g * 4 + r;  // lane holding this row's l (row16 == g*4+r, g-copy 0)
      float lh = __shfl(lph[m], srcl);
      float ll = __shfl(lpl[m], srcl);
      float lih = __builtin_amdgcn_rcpf(lh);
      float lil = __builtin_amdgcn_rcpf(ll);
      int th = hq0 + m * 16 + g * 4 + r;
      int tl = lq0 + m * 16 + g * 4 + r;
#pragma unroll
      for (int nd = 0; nd < 4; ++nd) {
        ((short*)yb)[((size_t)(b * TT + th)) * CC + h * HD + nd * 16 + row16] =
            f2bf(acch[m][nd][r] * lih);
        ((short*)yb)[((size_t)(b * TT + tl)) * CC + h * HD + nd * 16 + row16] =
            f2bf(accl[m][nd][r] * lil);
      }
    }
}

// ---------------- GEMM2: out(fp32) = y(bf16) @ WpT^T, BK=64 -----------------
__global__ __launch_bounds__(256) void gemm_proj_kernel(const bf16* __restrict__ yb,
                                                        const bf16* __restrict__ WpT,
                                                        float* __restrict__ out) {
  __shared__ bf16 As[128 * 64];
  __shared__ bf16 Bs[128 * 64];
  const int tid = threadIdx.x;
  const int wid = tid >> 6, lane = tid & 63, row16 = lane & 15, g = lane >> 4;
  const int wr = wid >> 1, wc = wid & 1;
  const int mbase = blockIdx.x * 128, nbase = blockIdx.y * 128;

  f32x4 acc[4][4] = {};

  for (int kt = 0; kt < CC; kt += 64) {
#pragma unroll
    for (int i = 0; i < 4; ++i) {
      int chunk = i * 256 + tid;
      int row = chunk >> 3;
      int cb = ((chunk & 7) * 16) ^ ((row & 7) << 4);
      gload_lds16((const char*)(yb + (size_t)(mbase + row) * CC + kt) + cb,
                  (char*)As + chunk * 16);
      gload_lds16((const char*)(WpT + (size_t)(nbase + row) * CC + kt) + cb,
                  (char*)Bs + chunk * 16);
    }
    __syncthreads();
#pragma unroll
    for (int kk = 0; kk < 2; ++kk) {
      bf16x8 af[4], bfr[4];
#pragma unroll
      for (int m = 0; m < 4; ++m) {
        int row = wr * 64 + m * 16 + row16;
        af[m] = *(const bf16x8*)((char*)As +
                 ((row * 128 + kk * 64 + g * 16) ^ ((row & 7) << 4)));
      }
#pragma unroll
      for (int n = 0; n < 4; ++n) {
        int row = wc * 64 + n * 16 + row16;
        bfr[n] = *(const bf16x8*)((char*)Bs +
                 ((row * 128 + kk * 64 + g * 16) ^ ((row & 7) << 4)));
      }
#pragma unroll
      for (int m = 0; m < 4; ++m)
#pragma unroll
        for (int n = 0; n < 4; ++n)
          acc[m][n] = __builtin_amdgcn_mfma_f32_16x16x32_bf16(af[m], bfr[n], acc[m][n], 0, 0, 0);
    }
    __syncthreads();
  }
#pragma unroll
  for (int m = 0; m < 4; ++m) {
    int grow0 = mbase + wr * 64 + m * 16 + g * 4;
#pragma unroll
    for (int n = 0; n < 4; ++n) {
      int gcol = nbase + wc * 64 + n * 16 + row16;
#pragma unroll
      for (int r = 0; r < 4; ++r)
        out[(size_t)(grow0 + r) * CC + gcol] = acc[m][n][r];
    }
  }
}

// ---------------- launch ----------------------------------------------------
extern "C" void kernel_launch(void* const* d_in, const int* in_sizes, int n_in,
                              void* d_out, int out_size, void* d_ws, size_t ws_size,
                              hipStream_t stream) {
  const float* x      = (const float*)d_in[0];
  const float* W_attn = (const float*)d_in[1];
  const float* W_proj = (const float*)d_in[2];
  float* out = (float*)d_out;

  char* ws = (char*)d_ws;
  // layout: WaT 6MB | WpT 2MB | q 16MB | k 16MB | v 16MB | y 16MB (= 72MB)
  // x_bf (16MB) ALIASES the y region: x_bf is dead before attn writes y.
  bf16* WaT = (bf16*)(ws);
  bf16* WpT = (bf16*)(ws + 6291456);
  bf16* qb  = (bf16*)(ws + 8388608);
  bf16* kb  = (bf16*)(ws + 8388608 + 16777216);
  bf16* vb  = (bf16*)(ws + 8388608 + 2 * 16777216);
  bf16* yb  = (bf16*)(ws + 8388608 + 3 * 16777216);
  bf16* xbf = yb;

  prep_kernel<<<dim3(8192), 256, 0, stream>>>(x, xbf, W_attn, WaT, W_proj, WpT);
  gemm_qkv_kernel<<<dim3(MM / 128, N1 / 128), 256, 0, stream>>>(xbf, WaT, qb, kb, vb);
  attn_kernel<<<dim3(8, BB * HH), 256, 0, stream>>>(qb, kb, vb, yb);
  gemm_proj_kernel<<<dim3(MM / 128, CC / 128), 256, 0, stream>>>(yb, WpT, out);
}